// Round 1
// 118.833 us; speedup vs baseline: 1.0071x; 1.0071x over previous
//
#include <hip/hip_runtime.h>

#define ROWS 1024
#define PTS 6144              // points per batch row (2048*3)
#define NDIH (PTS - 3)        // 6141 dihedrals per row
#define ROWF (PTS * 3)        // 18432 floats per row
#define ROWF4 (ROWF / 4)      // 4608 float4 per row
#define CHUNK 1024            // dihedrals per block
#define DPT 4                 // dihedrals per thread
#define THREADS 256           // CHUNK / DPT
#define NCHUNK 6              // ceil(6141/1024)
#define ANG_PER_ROW (2 * NDIH)                // 12282
#define SFLOATS ((CHUNK + 3) * 3 + 3)         // 3084 floats = 12.3 KB
#define EPS_SHIFT 1e-8f

// Per-wave staging geometry: wave w's 64 threads read LDS floats
// [768w .. 768w+779]  (window f4 up to 192w+193, scalar tail s[768w+776]).
// => wave w loads float4 indices 192w .. 192w+194  (195 per wave).
// Adjacent waves' 3-f4 overlap is a benign duplicate load (same data).

__global__ __launch_bounds__(THREADS) void dih_kernel(const float* __restrict__ in,
                                                      float* __restrict__ out) {
    __shared__ float s[SFLOATS];
    const int b     = blockIdx.x / NCHUNK;
    const int chunk = blockIdx.x % NCHUNK;
    const int i0    = chunk * CHUNK;
    const int t     = threadIdx.x;
    const int wid   = t >> 6;
    const int lane  = t & 63;

    // ---- per-wave async global -> LDS staging (no VGPR round trip, no barrier) ----
    const float4* g4  = (const float4*)(in + (size_t)b * ROWF);
    const int cbase   = chunk * (CHUNK * 3 / 4);     // 768 * chunk, f4 index of chunk start
    #pragma unroll
    for (int p = 0; p < 4; ++p) {
        const int rel = p * 64 + lane;               // 0..255 within wave's slice
        const int f4i = 192 * wid + rel;             // LDS f4 destination index
        // rel<195: wave slice bound; cbase+f4i<ROWF4: last-chunk global bound
        if (rel < 195 && (cbase + f4i) < ROWF4) {
            __builtin_amdgcn_global_load_lds(
                (const __attribute__((address_space(1))) void*)(g4 + cbase + f4i),
                (__attribute__((address_space(3))) void*)(s + (192 * wid + p * 64) * 4),
                16, 0, 0);
        }
    }
    // wait only for THIS wave's loads; each wave reads only what it wrote
    asm volatile("s_waitcnt vmcnt(0)" ::: "memory");
    __builtin_amdgcn_sched_barrier(0);

    // first_three output (x[:, :3, :]) — once per row, from chunk 0 / wave 0
    if (chunk == 0 && t < 9)
        out[(size_t)ROWS * ANG_PER_ROW + (size_t)b * 9 + t] = s[t];

    // ---- 21-float window (points i0+4t .. i0+4t+6) via 5x ds_read_b128 + 1 ----
    float w[21];
    {
        const float4* ls4 = (const float4*)(s + 12 * t);
        float4 v0 = ls4[0], v1 = ls4[1], v2 = ls4[2], v3 = ls4[3], v4 = ls4[4];
        w[0]=v0.x;  w[1]=v0.y;  w[2]=v0.z;  w[3]=v0.w;
        w[4]=v1.x;  w[5]=v1.y;  w[6]=v1.z;  w[7]=v1.w;
        w[8]=v2.x;  w[9]=v2.y;  w[10]=v2.z; w[11]=v2.w;
        w[12]=v3.x; w[13]=v3.y; w[14]=v3.z; w[15]=v3.w;
        w[16]=v4.x; w[17]=v4.y; w[18]=v4.z; w[19]=v4.w;
        w[20]=s[12 * t + 20];
    }

    // ---- shared edge differences e_j = x_j - x_{j+1}, j = 0..5 ----
    float ex[6], ey[6], ez[6];
    #pragma unroll
    for (int j = 0; j < 6; ++j) {
        ex[j] = w[3*j + 0] - w[3*j + 3];
        ey[j] = w[3*j + 1] - w[3*j + 4];
        ez[j] = w[3*j + 2] - w[3*j + 5];
    }

    float sv[DPT], cv[DPT];
    #pragma unroll
    for (int k = 0; k < DPT; ++k) {
        const float brx = ex[k+1] + EPS_SHIFT;
        const float bry = ey[k+1] + EPS_SHIFT;
        const float brz = ez[k+1] + EPS_SHIFT;
        const float nrm2 = brx*brx + bry*bry + brz*brz;
        const float inv = rsqrtf(fmaxf(nrm2, 1e-24f));   // 1/clip(|bc|,1e-12)
        const float ux = brx * inv, uy = bry * inv, uz = brz * inv;

        // n1 = cross(a-b, u)
        const float n1x = ey[k]*uz - ez[k]*uy;
        const float n1y = ez[k]*ux - ex[k]*uz;
        const float n1z = ex[k]*uy - ey[k]*ux;
        // n2 = cross(u, c-d)
        const float n2x = uy*ez[k+2] - uz*ey[k+2];
        const float n2y = uz*ex[k+2] - ux*ez[k+2];
        const float n2z = ux*ey[k+2] - uy*ex[k+2];

        const float xc = n1x*n2x + n1y*n2y + n1z*n2z;
        // m = cross(n1, u)
        const float mx = n1y*uz - n1z*uy;
        const float my = n1z*ux - n1x*uz;
        const float mz = n1x*uy - n1y*ux;
        const float yc = mx*n2x + my*n2y + mz*n2z;

        const float xz = xc + EPS_SHIFT;
        const float r2 = yc*yc + xz*xz;
        const float rinv = rsqrtf(fmaxf(r2, 1e-30f));
        sv[k] = (r2 > 0.0f) ? yc * rinv : 0.0f;
        cv[k] = (r2 > 0.0f) ? xz * rinv : 1.0f;
    }

    // ---- direct global stores, no barriers, no LDS transpose ----
    // sin base (b*12282 + i0 + 4t) is even -> float2 (8B) aligned.
    // cos base is odd (NDIH=6141) -> 4 adjacent scalar dwords; the wave's 6
    // store instrs cover a contiguous 1KB region -> L2 write-combines.
    const size_t obase = (size_t)b * ANG_PER_ROW;
    float* so = out + obase + i0;
    float* co = out + obase + NDIH + i0;
    const int j0    = 4 * t;
    const int valid = NDIH - i0;                 // >=1024 normally, 1021 last chunk
    if (j0 + 3 < valid) {
        *(float2*)(so + j0)     = make_float2(sv[0], sv[1]);
        *(float2*)(so + j0 + 2) = make_float2(sv[2], sv[3]);
        co[j0+0] = cv[0]; co[j0+1] = cv[1]; co[j0+2] = cv[2]; co[j0+3] = cv[3];
    } else {
        #pragma unroll
        for (int k = 0; k < 4; ++k)
            if (j0 + k < valid) { so[j0+k] = sv[k]; co[j0+k] = cv[k]; }
    }
}

extern "C" void kernel_launch(void* const* d_in, const int* in_sizes, int n_in,
                              void* d_out, int out_size, void* d_ws, size_t ws_size,
                              hipStream_t stream) {
    const float* in = (const float*)d_in[0];
    float* out = (float*)d_out;
    dih_kernel<<<dim3(ROWS * NCHUNK), dim3(THREADS), 0, stream>>>(in, out);
}